// Round 7
// baseline (138.479 us; speedup 1.0000x reference)
//
#include <hip/hip_runtime.h>

#define UNITS 256
#define NB 501               // num buckets
#define NBA 502              // A-table entries per unit (A[501] needed for idx=500)
#define STEPF 0.05f
#define LBF -17.0f
#define UBF 8.0f
#define RESIDUEF -17.05f     // LB - STEP
#define LOG2E 1.4426950408889634f

#define WLO 281              // hot window idx [281,432) -> x in [-3.0, 4.55)
#define WSZ 151              // iw in [0,151); P(cold) ~ 1.4e-3 (~23K elements)
#define WENT 152             // entries stored per unit (A[iw+1] needs +1)
#define PADF 153             // LDS row stride in floats; 256*153*4 = 156672 B
#define THREADS 1024         // 16 waves; 1 block/CU (LDS-capped)
#define ROWS_PB 256          // grid = 65536/256 = 256 blocks = 1/CU
#define CHUNKS 16            // 16 steps of 16 rows
#define RD 3                 // fenced ring depth (4 slots) -- r6 structure,
                             // proven to hold registers (VGPR=24, ring live)

// native vector type: works with __builtin_nontemporal_store (HIP float4 is a
// class type and is rejected)
typedef float floatx4 __attribute__((ext_vector_type(4)));

// ---------------------------------------------------------------------------
// Kernel 1: A-table -> d_ws (256*502*4 B = 514 KB, L2/L3-resident).
//   A[u,j] = (STEP * excl_cumsum(relu(v))[j] + RESIDUE + b[u]) * LOG2E
// Interp identity: A[j+1]-A[j] = STEP*w[j]*LOG2E, so
//   log2e*logit = A[idx] + frac*(A[idx+1]-A[idx]),  frac = t*20 - idx.
// One wave per unit, 8 entries/lane (covers j through 511 >= 502).
// ---------------------------------------------------------------------------
__global__ __launch_bounds__(256) void build_table_kernel(
    const float* __restrict__ v, const float* __restrict__ b,
    float* __restrict__ gtab) {
  const int lane = threadIdx.x & 63;
  const int wave = threadIdx.x >> 6;
  const int u = blockIdx.x * 4 + wave;
  if (u >= UNITS) return;

  const float* vu = v + u * NB;
  float pref[8];
  float run = 0.0f;
#pragma unroll
  for (int k = 0; k < 8; ++k) {
    const int j = lane * 8 + k;
    const float wv = (j < NB) ? fmaxf(vu[j], 0.0f) : 0.0f;
    pref[k] = run;  // exclusive within-lane prefix
    run += wv;
  }
  float s = run;    // inclusive wave scan of per-lane sums
#pragma unroll
  for (int d = 1; d < 64; d <<= 1) {
    const float o = __shfl_up(s, d, 64);
    if (lane >= d) s += o;
  }
  const float base = s - run;  // exclusive lane base
  const float off = RESIDUEF + b[u];
#pragma unroll
  for (int k = 0; k < 8; ++k) {
    const int j = lane * 8 + k;
    if (j < NBA) {
      gtab[u * NBA + j] = (STEPF * (base + pref[k]) + off) * LOG2E;
    }
  }
}

// ---------------------------------------------------------------------------
// Kernel 2: stream x -> out.  256 blocks (1/CU), 1024 threads, FULL-ROW tiles:
// per block 256 rows x ALL 256 units.
//
// ROUND-7 THEORY: every prior round column-sliced the row (128/256 B slices at
// 1 KB stride). HBM channel interleaving is fine-grained (~256 B), so a
// 1 KB-strided stream touches ~1/4 of the channels; the complementary blocks
// are time-unaligned on other XCDs -> ~2.2 TB/s ceiling observed in rounds
// 0-6 regardless of CU-side structure, while the contiguous fill kernel hits
// 6.3 TB/s. Fix: one wave-load (64 x float4 = 1 KB) = exactly one FULL row;
// each block streams contiguous 256 KB spans in and out, fill-like.
// Requires the full 256-unit hot window in LDS: window shrunk to x in
// [-3.0, 4.55) -> 152 f32/unit, 156672 B (1 block/CU). Cold path (~0.14%,
// mostly x < -3) falls back to the L2-resident gtab.
// Ring: r6's sched_barrier-fenced depth-3 ring (proven live, VGPR=24).
// ---------------------------------------------------------------------------
__global__ __launch_bounds__(THREADS, 4) void iso_main_kernel(
    const float* __restrict__ x, const float* __restrict__ gtab,
    float* __restrict__ out) {
  __shared__ float tab[UNITS * PADF];  // 156672 B

  const int bb = blockIdx.x;                // batch tile 0..255
  const int tid = threadIdx.x;

  // ---- stage hot window: linear-coalesced, 38 iters (256*152/1024) ----
  for (int i = tid; i < UNITS * WENT; i += THREADS) {
    const int ul = i / WENT;                // constant div -> mul/shift
    const int j = i - ul * WENT;
    tab[ul * PADF + j] = gtab[ul * NBA + WLO + j];
  }

  // ---- addressing: wave w covers the FULL row (bb*256 + step*16 + w) ----
  const int rw = tid >> 6;                  // row-within-step 0..15
  const int c4 = tid & 63;                  // float4 col 0..63 (lane id)
  const floatx4* __restrict__ x4 = reinterpret_cast<const floatx4*>(x);
  floatx4* __restrict__ o4 = reinterpret_cast<floatx4*>(out);
  const int g0 = (bb * ROWS_PB + rw) * (UNITS / 4) + c4;
  const int gstep = 16 * (UNITS / 4);       // 16 rows per step
  const int qrow = c4 * 4;                  // this thread's first unit

  __syncthreads();  // only barrier; staging drained, no x-loads in flight yet

  // ---- depth-3 fenced ring over 16 steps ----
  floatx4 xv[4];    // fully unrolled below -> compile-time slot indices
#pragma unroll
  for (int c = 0; c < RD; ++c) xv[c] = x4[g0 + c * gstep];
  __builtin_amdgcn_sched_barrier(0);        // prologue loads issued here

#pragma unroll
  for (int c = 0; c < CHUNKS; ++c) {
    if (c + RD < CHUNKS)
      xv[(c + RD) & 3] = x4[g0 + (c + RD) * gstep];
    __builtin_amdgcn_sched_barrier(0);      // load issued before compute

    const floatx4 cur = xv[c & 3];
    const float xs[4] = {cur.x, cur.y, cur.z, cur.w};
    float os[4];
#pragma unroll
    for (int k = 0; k < 4; ++k) {
      const float xc = fminf(fmaxf(xs[k], LBF + 1e-9f), UBF - 1e-9f);
      const float t = xc - LBF + STEPF;     // xc + 17.05, in (0.05, 25.05)
      const float ft = t * 20.0f;           // 1/STEP == 20
      const int idx = (int)ft;              // bucket, 1..500
      const float f = ft - (float)idx;      // frac in [0,1)
      const unsigned iw = (unsigned)(idx - WLO);
      float a0, a1;
      if (iw < WSZ) {                       // hot: one ds_read2_b32
        const float* p = &tab[(qrow + k) * PADF + (int)iw];
        a0 = p[0];
        a1 = p[1];
      } else {                              // ~0.14% of elements: L2 hit
        const int ci = idx < 1 ? 1 : (idx > NB - 1 ? NB - 1 : idx);
        const float* g = gtab + (qrow + k) * NBA + ci;
        a0 = g[0];
        a1 = g[1];
      }
      const float l2 = fmaf(f, a1 - a0, a0);  // log2e * logit
      const float e = __builtin_amdgcn_exp2f(-l2);
      os[k] = __builtin_amdgcn_rcpf(1.0f + e);
    }
    // write-once output: nt store keeps the 64 MB stream out of L2/L3
    floatx4 ov;
    ov.x = os[0]; ov.y = os[1]; ov.z = os[2]; ov.w = os[3];
    __builtin_nontemporal_store(ov, &o4[g0 + c * gstep]);
    __builtin_amdgcn_sched_barrier(0);      // store stays in its chunk
  }
}

extern "C" void kernel_launch(void* const* d_in, const int* in_sizes, int n_in,
                              void* d_out, int out_size, void* d_ws,
                              size_t ws_size, hipStream_t stream) {
  const float* x = (const float*)d_in[0];   // (65536, 256)
  const float* v = (const float*)d_in[1];   // (256, 501)
  const float* b = (const float*)d_in[2];   // (256,)
  float* out = (float*)d_out;               // (65536, 256)
  float* gtab = (float*)d_ws;               // 256*502*4 B = 514 KB

  build_table_kernel<<<64, 256, 0, stream>>>(v, b, gtab);

  const int rows = out_size / UNITS;        // 65536
  const int grid = rows / ROWS_PB;          // 256 = 1 block/CU
  iso_main_kernel<<<grid, THREADS, 0, stream>>>(x, gtab, out);
}

// Round 8
// 128.665 us; speedup vs baseline: 1.0763x; 1.0763x over previous
//
#include <hip/hip_runtime.h>

#define UNITS 256
#define NB 501               // num buckets
#define STEPF 0.05f
#define LBF -17.0f
#define UBF 8.0f
#define RESIDUEF -17.05f     // LB - STEP
#define LOG2E 1.4426950408889634f

#define WLO 208              // hot window idx [208,432) -> x in [-6.65, 4.55)
#define WSZ 224              // P(cold) ~ 2.7e-6 -> ~45 elements take global path
#define UPB 32               // units per block; LDS = 32*225*8 = 57600 B
#define PADF2 225            // LDS row stride in float2 (odd -> bank stagger)
#define THREADS 1024         // 16 waves/block
#define ROWS_PB 1024         // grid = 8 unit-tiles * 64 row-tiles = 512 = 2/CU
#define CHUNKS 8             // 8 chunks of 128 rows
#define RD 3                 // fenced ring depth (4 slots) -- r6-proven live

// native vector type: works with __builtin_nontemporal_store and as a 128-bit
// "v" inline-asm operand (HIP float4 is a class type; neither works)
typedef float floatx4 __attribute__((ext_vector_type(4)));

// ---------------------------------------------------------------------------
// Kernel 1: full fused table -> d_ws (1.03 MB, L2-resident).
//   w  = relu(v[u,j])
//   C  = STEP*excl_cumsum(w)[j] + RESIDUE + b[u] - j*STEP*w
//   store (C*log2e, w*log2e):  sigmoid = rcp(1 + exp2(-(C2 + t*w2))),
//   t = clamp(x)+17.05.  One wave per unit, 8 buckets/lane.
// float2 format -> kernel 2 does ONE aligned ds_read_b64 per element
// (r5-r7's 4B interp table forced two ds_read_b32: 4-byte alignment only).
// ---------------------------------------------------------------------------
__global__ __launch_bounds__(256) void build_table_kernel(
    const float* __restrict__ v, const float* __restrict__ b,
    float2* __restrict__ gtab) {
  const int lane = threadIdx.x & 63;
  const int wave = threadIdx.x >> 6;
  const int u = blockIdx.x * 4 + wave;
  if (u >= UNITS) return;

  const float* vu = v + u * NB;
  float w[8], pref[8];
  float run = 0.0f;
#pragma unroll
  for (int k = 0; k < 8; ++k) {
    const int j = lane * 8 + k;
    const float wv = (j < NB) ? fmaxf(vu[j], 0.0f) : 0.0f;
    w[k] = wv;
    pref[k] = run;  // exclusive within-lane prefix
    run += wv;
  }
  float s = run;    // inclusive wave scan of per-lane sums
#pragma unroll
  for (int d = 1; d < 64; d <<= 1) {
    const float o = __shfl_up(s, d, 64);
    if (lane >= d) s += o;
  }
  const float base = s - run;  // exclusive lane base
  const float off = RESIDUEF + b[u];
#pragma unroll
  for (int k = 0; k < 8; ++k) {
    const int j = lane * 8 + k;
    if (j < NB) {
      const float C = STEPF * (base + pref[k]) + off - (float)j * STEPF * w[k];
      gtab[u * NB + j] = make_float2(C * LOG2E, w[k] * LOG2E);
    }
  }
}

// ---------------------------------------------------------------------------
// Kernel 2: stream x -> out.  Per block: 32 units x 1024 rows, 1024 threads.
// Merge of the two best-measured structures:
//  - r4 geometry: float2 hot window (57600 B -> 2 blocks/CU so one block's
//    read bursts overlap the sibling's write bursts), 8x128-row chunks,
//    128 B contiguous wave-load segments, NT stores.
//  - r6 pipeline: depth-3 ring fenced with sched_barrier(0) -- verified to
//    keep the ring live in VGPRs (r6: VGPR=24, precise counted vmcnt waits,
//    loads issued 3 chunks (~10K cyc) ahead of use, never blocked by stores).
// Pre-committed read: if this still lands 43-48 us, the ~2.2-2.5 TB/s
// mixed-R/W wall is the platform roofline for this op (100 MB floor).
// ---------------------------------------------------------------------------
__global__ __launch_bounds__(THREADS, 8) void iso_main_kernel(
    const float* __restrict__ x, const float2* __restrict__ gtab,
    float* __restrict__ out) {
  __shared__ float2 tab[UPB * PADF2];  // 57600 B

  const int bu = blockIdx.x & 7;            // unit tile 0..7 (UPB=32)
  const int bb = blockIdx.x >> 3;           // batch tile 0..63
  const int u0 = bu * UPB;
  const int tid = threadIdx.x;

  // ---- stage hot window: 32 threads per unit, 7 float2 each ----
  {
    const int ul = tid >> 5;                // unit 0..31
    const int jt = tid & 31;
    const float2* __restrict__ src = gtab + (u0 + ul) * NB + WLO;
    float2* __restrict__ dst = tab + ul * PADF2;
#pragma unroll
    for (int r = 0; r < 7; ++r) {           // 7*32 = 224 entries, 256 B runs
      const int j = jt + r * 32;
      dst[j] = src[j];
    }
  }

  // ---- addressing ----
  const int rowoff = tid >> 3;              // 0..127 within chunk
  const int col4 = tid & 7;                 // float4 col within 32-unit span
  const floatx4* __restrict__ x4 = reinterpret_cast<const floatx4*>(x);
  floatx4* __restrict__ o4 = reinterpret_cast<floatx4*>(out);
  const int g0 = (bb * ROWS_PB + rowoff) * (UNITS / 4) + bu * (UPB / 4) + col4;
  const int gstep = 128 * (UNITS / 4);      // 128 rows per chunk
  const int qbase = (col4 * 4) * PADF2;     // LDS base for this thread's units

  // ---- prologue: issue ring loads, pin them live, then the only barrier ----
  floatx4 xv[4];    // fully unrolled below -> compile-time slot indices
#pragma unroll
  for (int c = 0; c < RD; ++c) xv[c] = x4[g0 + c * gstep];
#pragma unroll
  for (int c = 0; c < RD; ++c) asm volatile("" : "+v"(xv[c]));
  __syncthreads();

  // ---- depth-3 fenced ring over 8 chunks ----
#pragma unroll
  for (int c = 0; c < CHUNKS; ++c) {
    if (c + RD < CHUNKS)
      xv[(c + RD) & 3] = x4[g0 + (c + RD) * gstep];
    __builtin_amdgcn_sched_barrier(0);      // load issued before compute

    const floatx4 cur = xv[c & 3];
    const float xs[4] = {cur.x, cur.y, cur.z, cur.w};
    float os[4];
#pragma unroll
    for (int k = 0; k < 4; ++k) {
      const float xc = fminf(fmaxf(xs[k], LBF + 1e-9f), UBF - 1e-9f);
      const float t = xc - LBF + STEPF;     // xc + 17.05, in (0.05, 25.05)
      int idx = (int)(t * 20.0f);           // 1/STEP == 20 exactly
      const unsigned iw = (unsigned)(idx - WLO);
      float2 cw;
      if (iw < WSZ) {                       // hot: one aligned ds_read_b64
        cw = tab[qbase + k * PADF2 + (int)iw];
      } else {                              // ~45 elements total: L2 hit
        idx = idx < 0 ? 0 : (idx > NB - 1 ? NB - 1 : idx);
        cw = gtab[(u0 + col4 * 4 + k) * NB + idx];
      }
      const float l2 = fmaf(t, cw.y, cw.x); // log2e * logit
      const float e = __builtin_amdgcn_exp2f(-l2);
      os[k] = __builtin_amdgcn_rcpf(1.0f + e);
    }
    // write-once output: nt store keeps the 64 MB stream out of L2/L3
    floatx4 ov;
    ov.x = os[0]; ov.y = os[1]; ov.z = os[2]; ov.w = os[3];
    __builtin_nontemporal_store(ov, &o4[g0 + c * gstep]);
    __builtin_amdgcn_sched_barrier(0);      // store stays in its chunk
  }
}

extern "C" void kernel_launch(void* const* d_in, const int* in_sizes, int n_in,
                              void* d_out, int out_size, void* d_ws,
                              size_t ws_size, hipStream_t stream) {
  const float* x = (const float*)d_in[0];   // (65536, 256)
  const float* v = (const float*)d_in[1];   // (256, 501)
  const float* b = (const float*)d_in[2];   // (256,)
  float* out = (float*)d_out;               // (65536, 256)
  float2* gtab = (float2*)d_ws;             // 256*501*8 B = 1.03 MB

  build_table_kernel<<<64, 256, 0, stream>>>(v, b, gtab);

  const int rows = out_size / UNITS;                  // 65536
  const int grid = (UNITS / UPB) * (rows / ROWS_PB);  // 8 * 64 = 512
  iso_main_kernel<<<grid, THREADS, 0, stream>>>(x, gtab, out);
}